// Round 9
// baseline (787.334 us; speedup 1.0000x reference)
//
#include <hip/hip_runtime.h>
#include <hip/hip_bf16.h>
#include <cstdint>
#include <cstddef>

#define M_ 4096
#define K_ 7168
#define N_ 18432
#define NT 112  // K-tiles of BK=64

typedef __attribute__((ext_vector_type(4))) int i32x4;
typedef __attribute__((ext_vector_type(16))) int i32x16;

#define AS1 __attribute__((address_space(1)))
#define AS3 __attribute__((address_space(3)))

__device__ __forceinline__ void gld_lds16(void* lds, const void* g) {
  __builtin_amdgcn_global_load_lds((const AS1 void*)g, (AS3 void*)lds, 16, 0, 0);
}

// ---------------- prepass 1: per-row dynamic quantization of x ----------------
__global__ __launch_bounds__(256) void quant_x_kernel(const float* __restrict__ x,
                                                      signed char* __restrict__ xq,
                                                      float* __restrict__ sx) {
  const int m = blockIdx.x;
  const float4* row4 = (const float4*)(x + (size_t)m * K_);
  float mx = 0.f;
  for (int i = threadIdx.x; i < K_ / 4; i += 256) {
    float4 v = row4[i];
    mx = fmaxf(mx, fmaxf(fmaxf(fabsf(v.x), fabsf(v.y)), fmaxf(fabsf(v.z), fabsf(v.w))));
  }
#pragma unroll
  for (int d = 1; d < 64; d <<= 1) mx = fmaxf(mx, __shfl_xor(mx, d));
  __shared__ float wred[4];
  if ((threadIdx.x & 63) == 0) wred[threadIdx.x >> 6] = mx;
  __syncthreads();
  mx = fmaxf(fmaxf(wred[0], wred[1]), fmaxf(wred[2], wred[3]));
  const float inv = mx > 0.f ? 127.f / mx : 0.f;
  if (threadIdx.x == 0) sx[m] = mx / 127.f;
  char4* q4 = (char4*)(xq + (size_t)m * K_);
  for (int i = threadIdx.x; i < K_ / 4; i += 256) {
    float4 v = row4[i];
    char4 c;
    c.x = (signed char)__float2int_rn(v.x * inv);
    c.y = (signed char)__float2int_rn(v.y * inv);
    c.z = (signed char)__float2int_rn(v.z * inv);
    c.w = (signed char)__float2int_rn(v.w * inv);
    q4[i] = c;
  }
}

// ---- prepass 2: W int32 [K,N] -> Wt int8 [N,K] (convert + transpose) ----
__global__ __launch_bounds__(256) void transpose_w_kernel(const int* __restrict__ W,
                                                          signed char* __restrict__ Wt) {
  __shared__ __align__(16) signed char t[64][80];
  const int k0 = blockIdx.x * 64;
  const int n0 = blockIdx.y * 64;
  const int r = threadIdx.x >> 4;
  const int c4 = (threadIdx.x & 15) * 4;
#pragma unroll
  for (int rr = 0; rr < 4; ++rr) {
    const int row = rr * 16 + r;
    int4 v = *(const int4*)(W + (size_t)(k0 + row) * N_ + n0 + c4);
    t[c4 + 0][row] = (signed char)v.x;
    t[c4 + 1][row] = (signed char)v.y;
    t[c4 + 2][row] = (signed char)v.z;
    t[c4 + 3][row] = (signed char)v.w;
  }
  __syncthreads();
  const int nr = threadIdx.x >> 2;
  const int cb = (threadIdx.x & 3) * 16;
  int4 o = *(const int4*)&t[nr][cb];
  *(int4*)(Wt + (size_t)(n0 + nr) * K_ + k0 + cb) = o;
}

// ============ main GEMM: 256x256 tile, BK=64, 8-wave, 32x32x32 i8 MFMA ============
// Retimed pipeline (R8 post-mortem: post-barrier read burst serialized LDS & MFMA pipes):
//   tile t: STAGE(t+2 -> buf[t&1])           (buf consumed into regs during t-1)
//           MFMA8(bank0)  | LDFR bank0 <- tile t+1 k0   (buf[(t+1)&1], drained at end t-1)
//           MFMA8(bank1)  | LDFR bank1 <- tile t+1 k1
//           vmcnt(0); barrier                 (stage issued at tile top -> ~1-tile window)
// Every MFMA consumes reads issued one full tile earlier -> no lgkm stall; LDS pipe
// (~1152 cyc/tile) hides under MFMA pipe (~1170 cyc/tile).
// LDS: buf P at P*32768: A [0,16384) rows 0..255 x 64B, B [16384,32768).
// Swizzle (identical geometry to R8, measured 0 conflicts): physslot = slot ^ ((row>>2)&3).
__global__ __launch_bounds__(512, 2) void gemm_i8_kernel(const signed char* __restrict__ Aq,
                                                         const signed char* __restrict__ Bt,
                                                         const float* __restrict__ sx,
                                                         const float* __restrict__ scale,
                                                         float* __restrict__ C) {
  __shared__ __align__(16) signed char lds[65536];

  // n-major XCD mapping: each XCD owns 9 n-columns; active B panel ~2 cols ~3.7MB ~ L2.
  const int bid = blockIdx.x;
  const int xcd = bid & 7;
  const int j = bid >> 3;                     // 0..143
  const int m0 = (j & 15) * 256;              // 16 m-blocks
  const int n0 = (xcd * 9 + (j >> 4)) * 256;  // 72 n-blocks

  const int tid = threadIdx.x;
  const int w = tid >> 6;      // wave 0..7
  const int lane = tid & 63;
  const int wr = w >> 2;       // 0..1 (M)
  const int wc = w & 3;        // 0..3 (N)

  // 32x32 fragment addressing: lane holds row (lane&31), k-half (lane>>5)*16B
  const int fr32 = lane & 31;
  const int kh = lane >> 5;
  const int sw = (fr32 >> 2) & 3;
  const int ps0 = ((kh ^ sw) << 4);  // phys slot*16 for k-step 0
  const int ps1 = ps0 ^ 0x20;        // for k-step 1
  const int rA = (wr * 128 + fr32) * 64;
  const int rB = 16384 + (wc * 64 + fr32) * 64;

  // staging per-lane (inverse-swizzled global source, linear LDS dest)
  // phys row pr = j*128 + w*16 + (lane>>2) -> (pr>>2)&3 = (lane>>4)&3
  const int ls16 = (((lane & 3) ^ ((lane >> 4) & 3)) << 4);
  const int pr0 = w * 16 + (lane >> 2);
  const unsigned offA0 = (unsigned)(m0 + pr0) * K_ + ls16;
  const unsigned offA1 = (unsigned)(m0 + 128 + pr0) * K_ + ls16;
  const unsigned offB0 = (unsigned)(n0 + pr0) * K_ + ls16;
  const unsigned offB1 = (unsigned)(n0 + 128 + pr0) * K_ + ls16;

// stage tile T (BK=64: 2 A-loads + 2 B-loads per wave) into buf P
#define STAGE(T, P) do {                                                           \
    const int tc_ = (T) < NT ? (T) : NT - 1;                                       \
    signed char* dA_ = lds + (P) * 32768 + w * 1024;                               \
    gld_lds16(dA_, Aq + (size_t)offA0 + tc_ * 64);                                 \
    gld_lds16(dA_ + 8192, Aq + (size_t)offA1 + tc_ * 64);                          \
    signed char* dB_ = dA_ + 16384;                                                \
    gld_lds16(dB_, Bt + (size_t)offB0 + tc_ * 64);                                 \
    gld_lds16(dB_ + 8192, Bt + (size_t)offB1 + tc_ * 64);                          \
  } while (0)
// read one k-step's fragments into a bank: 4 A-frags + 2 B-frags (6 x ds_read_b128)
#define LDFR(FA, FB, P, KST) do {                                                  \
    const signed char* base_ = lds + (P) * 32768 + ((KST) ? ps1 : ps0);            \
    _Pragma("unroll") for (int mt_ = 0; mt_ < 4; ++mt_)                            \
      FA[mt_] = *(const i32x4*)(base_ + rA + mt_ * 2048);                          \
    _Pragma("unroll") for (int nt_ = 0; nt_ < 2; ++nt_)                            \
      FB[nt_] = *(const i32x4*)(base_ + rB + nt_ * 2048);                          \
  } while (0)
#define MFMA8(FA, FB) do {                                                         \
    __builtin_amdgcn_s_setprio(1);                                                 \
    _Pragma("unroll") for (int mt_ = 0; mt_ < 4; ++mt_)                            \
    _Pragma("unroll") for (int nt_ = 0; nt_ < 2; ++nt_)                            \
      acc[mt_][nt_] = __builtin_amdgcn_mfma_i32_32x32x32_i8(                       \
          FA[mt_], FB[nt_], acc[mt_][nt_], 0, 0, 0);                               \
    __builtin_amdgcn_s_setprio(0);                                                 \
  } while (0)
#define BAR do { asm volatile("" ::: "memory");                                    \
                 __builtin_amdgcn_s_barrier();                                     \
                 asm volatile("" ::: "memory"); } while (0)
#define VM0 asm volatile("s_waitcnt vmcnt(0)" ::: "memory")
#define LGKM0 asm volatile("s_waitcnt lgkmcnt(0)" ::: "memory")
#define SB __builtin_amdgcn_sched_barrier(0)

// tile T in buf P: MFMAs consume banks (loaded during T-1); LDFRs prefetch tile T+1
#define KTILE(P, T) do {                                                           \
    STAGE((T) + 2, P); SB;                                                         \
    MFMA8(fA0, fB0); LDFR(fA0, fB0, (P) ^ 1, 0); SB;                               \
    MFMA8(fA1, fB1); LDFR(fA1, fB1, (P) ^ 1, 1); SB;                               \
    VM0;  /* stage(T+2) drains; ~1-tile window since issue */                      \
    BAR;  /* all waves: tile T+2 in LDS; banks hold tile T+1 */                    \
  } while (0)

  i32x16 acc[4][2] = {};
  i32x4 fA0[4], fB0[2], fA1[4], fB1[2];

  // Prologue: stage tiles 0,1; drain; read tile0 into banks; fence reads before
  // the loop's first STAGE(2 -> buf0) can overwrite buf0.
  STAGE(0, 0); STAGE(1, 1);
  VM0;
  BAR;
  LDFR(fA0, fB0, 0, 0); LDFR(fA1, fB1, 0, 1);
  LGKM0; SB;
  BAR;

  for (int t = 0; t < NT; t += 2) {
    KTILE(0, t);      // compute tile t   (banks), prefetch t+1, stage t+2 -> buf0
    KTILE(1, t + 1);  // compute tile t+1 (banks), prefetch t+2, stage t+3 -> buf1
  }

  // epilogue: y = i32acc * sx[m] * scale[n]
  // C/D 32x32: col = lane&31, row = (reg&3) + 8*(reg>>2) + 4*(lane>>5)
  const int mb = m0 + wr * 128;
  const int nb = n0 + wc * 64;
  const int col = lane & 31;
  const int rhi = (lane >> 5) * 4;
  const float scl0 = scale[nb + col];
  const float scl1 = scale[nb + 32 + col];
#pragma unroll
  for (int mt = 0; mt < 4; ++mt) {
#pragma unroll
    for (int r = 0; r < 16; ++r) {
      const int row = mb + mt * 32 + (r & 3) + (r >> 2) * 8 + rhi;
      const float s = sx[row];
      float* out = C + (size_t)row * N_ + nb + col;
      out[0]  = (float)acc[mt][0][r] * s * scl0;
      out[32] = (float)acc[mt][1][r] * s * scl1;
    }
  }
#undef STAGE
#undef LDFR
#undef MFMA8
#undef BAR
#undef VM0
#undef LGKM0
#undef SB
#undef KTILE
}

// ---------------- fallback (only if ws_size too small): tiled fp32 vector GEMM ----------------
__global__ __launch_bounds__(256) void fb_gemm_kernel(const float* __restrict__ X,
                                                      const int* __restrict__ W,
                                                      const float* __restrict__ scale,
                                                      float* __restrict__ Y) {
  __shared__ float xs[16][65];
  __shared__ float ws_[16][65];
  const int bn = blockIdx.x * 64;
  const int bm = blockIdx.y * 64;
  const int tx = threadIdx.x & 15;
  const int ty = threadIdx.x >> 4;
  float acc[4][4] = {};
  for (int k0 = 0; k0 < K_; k0 += 16) {
    for (int i = threadIdx.x; i < 64 * 16; i += 256) {
      int r = i >> 4, c = i & 15;
      xs[c][r] = X[(size_t)(bm + r) * K_ + k0 + c];
    }
    for (int i = threadIdx.x; i < 16 * 64; i += 256) {
      int r = i >> 6, c = i & 63;
      ws_[r][c] = (float)W[(size_t)(k0 + r) * N_ + bn + c];
    }
    __syncthreads();
#pragma unroll
    for (int kk = 0; kk < 16; ++kk) {
      float a[4], b[4];
#pragma unroll
      for (int i = 0; i < 4; ++i) a[i] = xs[kk][ty * 4 + i];
#pragma unroll
      for (int j = 0; j < 4; ++j) b[j] = ws_[kk][tx * 4 + j];
#pragma unroll
      for (int i = 0; i < 4; ++i)
#pragma unroll
        for (int j = 0; j < 4; ++j) acc[i][j] += a[i] * b[j];
    }
    __syncthreads();
  }
#pragma unroll
  for (int i = 0; i < 4; ++i)
#pragma unroll
    for (int j = 0; j < 4; ++j)
      Y[(size_t)(bm + ty * 4 + i) * N_ + bn + tx * 4 + j] = acc[i][j] * scale[bn + tx * 4 + j];
}

extern "C" void kernel_launch(void* const* d_in, const int* in_sizes, int n_in,
                              void* d_out, int out_size, void* d_ws, size_t ws_size,
                              hipStream_t stream) {
  const float* x = (const float*)d_in[0];
  const int* w = (const int*)d_in[1];  // harness materializes int8 weights as int32
  const float* scale = (const float*)d_in[2];
  float* y = (float*)d_out;

  const size_t xq_bytes = (size_t)M_ * K_;
  const size_t sx_off = xq_bytes;
  const size_t wt_off = sx_off + (size_t)M_ * 4;
  const size_t need = wt_off + (size_t)N_ * K_;  // ~161.5 MB

  if (ws_size >= need) {
    signed char* xq = (signed char*)d_ws;
    float* sx = (float*)((char*)d_ws + sx_off);
    signed char* wt = (signed char*)((char*)d_ws + wt_off);
    hipLaunchKernelGGL(quant_x_kernel, dim3(M_), dim3(256), 0, stream, x, xq, sx);
    hipLaunchKernelGGL(transpose_w_kernel, dim3(K_ / 64, N_ / 64), dim3(256), 0, stream, w, wt);
    hipLaunchKernelGGL(gemm_i8_kernel, dim3((M_ / 256) * (N_ / 256)), dim3(512), 0, stream,
                       xq, wt, sx, scale, y);
  } else {
    hipLaunchKernelGGL(fb_gemm_kernel, dim3(N_ / 64, M_ / 64), dim3(256), 0, stream,
                       x, w, scale, y);
  }
}

// Round 11
// 735.123 us; speedup vs baseline: 1.0710x; 1.0710x over previous
//
#include <hip/hip_runtime.h>
#include <hip/hip_bf16.h>
#include <cstdint>
#include <cstddef>

#define M_ 4096
#define K_ 7168
#define N_ 18432
#define NT 112  // K-tiles of BK=64

typedef __attribute__((ext_vector_type(4))) int i32x4;
typedef __attribute__((ext_vector_type(16))) int i32x16;

#define AS1 __attribute__((address_space(1)))
#define AS3 __attribute__((address_space(3)))

__device__ __forceinline__ void gld_lds16(void* lds, const void* g) {
  __builtin_amdgcn_global_load_lds((const AS1 void*)g, (AS3 void*)lds, 16, 0, 0);
}

// ---------------- prepass 1: per-row dynamic quantization of x ----------------
__global__ __launch_bounds__(256) void quant_x_kernel(const float* __restrict__ x,
                                                      signed char* __restrict__ xq,
                                                      float* __restrict__ sx) {
  const int m = blockIdx.x;
  const float4* row4 = (const float4*)(x + (size_t)m * K_);
  float mx = 0.f;
  for (int i = threadIdx.x; i < K_ / 4; i += 256) {
    float4 v = row4[i];
    mx = fmaxf(mx, fmaxf(fmaxf(fabsf(v.x), fabsf(v.y)), fmaxf(fabsf(v.z), fabsf(v.w))));
  }
#pragma unroll
  for (int d = 1; d < 64; d <<= 1) mx = fmaxf(mx, __shfl_xor(mx, d));
  __shared__ float wred[4];
  if ((threadIdx.x & 63) == 0) wred[threadIdx.x >> 6] = mx;
  __syncthreads();
  mx = fmaxf(fmaxf(wred[0], wred[1]), fmaxf(wred[2], wred[3]));
  const float inv = mx > 0.f ? 127.f / mx : 0.f;
  if (threadIdx.x == 0) sx[m] = mx / 127.f;
  char4* q4 = (char4*)(xq + (size_t)m * K_);
  for (int i = threadIdx.x; i < K_ / 4; i += 256) {
    float4 v = row4[i];
    char4 c;
    c.x = (signed char)__float2int_rn(v.x * inv);
    c.y = (signed char)__float2int_rn(v.y * inv);
    c.z = (signed char)__float2int_rn(v.z * inv);
    c.w = (signed char)__float2int_rn(v.w * inv);
    q4[i] = c;
  }
}

// ---- prepass 2: W int32 [K,N] -> Wt int8 [N,K] (convert + transpose) ----
__global__ __launch_bounds__(256) void transpose_w_kernel(const int* __restrict__ W,
                                                          signed char* __restrict__ Wt) {
  __shared__ __align__(16) signed char t[64][80];
  const int k0 = blockIdx.x * 64;
  const int n0 = blockIdx.y * 64;
  const int r = threadIdx.x >> 4;
  const int c4 = (threadIdx.x & 15) * 4;
#pragma unroll
  for (int rr = 0; rr < 4; ++rr) {
    const int row = rr * 16 + r;
    int4 v = *(const int4*)(W + (size_t)(k0 + row) * N_ + n0 + c4);
    t[c4 + 0][row] = (signed char)v.x;
    t[c4 + 1][row] = (signed char)v.y;
    t[c4 + 2][row] = (signed char)v.z;
    t[c4 + 3][row] = (signed char)v.w;
  }
  __syncthreads();
  const int nr = threadIdx.x >> 2;
  const int cb = (threadIdx.x & 3) * 16;
  int4 o = *(const int4*)&t[nr][cb];
  *(int4*)(Wt + (size_t)(n0 + nr) * K_ + k0 + cb) = o;
}

// ============ main GEMM: 256x256 tile, BK=64, 8-wave, 32x32x32 i8 MFMA ============
// Per-wave sched_group_barrier interleave (MFMA/ds_read at WAR granularity) so one
// wave's stream feeds both pipes (2-wave/SIMD phase-locked regime — R9 post-mortem).
// 4 LDS buffers (128 KB), stage t+3, counted vmcnt(4).
// LEDGER (fixed R10 prologue race): invariant entering KTILE(T): outstanding = 4
// (= tile T+2's stage). Prologue establishes it by draining tiles 0 AND 1 (VM4),
// leaving tile 2 in flight. KTILE(T): STAGE(T+3) -> 8 outstanding; LDFR reads tile
// T+1 (drained + barrier'd at end of T-1); VM4 at end drains tile T+2, leaves T+3.
// LDS: buf P at P*32768: A [0,16384), B [16384,32768).
// Swizzle (measured 0 conflicts): physslot = slot ^ ((row>>2)&3), inverse on gld source.
__global__ __launch_bounds__(512, 2) void gemm_i8_kernel(const signed char* __restrict__ Aq,
                                                         const signed char* __restrict__ Bt,
                                                         const float* __restrict__ sx,
                                                         const float* __restrict__ scale,
                                                         float* __restrict__ C) {
  __shared__ __align__(16) signed char lds[131072];

  // n-major XCD mapping: each XCD owns 9 n-columns.
  const int bid = blockIdx.x;
  const int xcd = bid & 7;
  const int j = bid >> 3;                     // 0..143
  const int m0 = (j & 15) * 256;              // 16 m-blocks
  const int n0 = (xcd * 9 + (j >> 4)) * 256;  // 72 n-blocks

  const int tid = threadIdx.x;
  const int w = tid >> 6;      // wave 0..7
  const int lane = tid & 63;
  const int wr = w >> 2;       // 0..1 (M)
  const int wc = w & 3;        // 0..3 (N)

  // 32x32 fragment addressing: lane holds row (lane&31), k-half (lane>>5)*16B
  const int fr32 = lane & 31;
  const int kh = lane >> 5;
  const int sw = (fr32 >> 2) & 3;
  const int ps0 = ((kh ^ sw) << 4);  // phys slot*16 for k-step 0
  const int ps1 = ps0 ^ 0x20;        // for k-step 1
  const int rA = (wr * 128 + fr32) * 64;
  const int rB = 16384 + (wc * 64 + fr32) * 64;

  // staging per-lane (inverse-swizzled global source, linear LDS dest)
  const int ls16 = (((lane & 3) ^ ((lane >> 4) & 3)) << 4);
  const int pr0 = w * 16 + (lane >> 2);
  const unsigned offA0 = (unsigned)(m0 + pr0) * K_ + ls16;
  const unsigned offA1 = (unsigned)(m0 + 128 + pr0) * K_ + ls16;
  const unsigned offB0 = (unsigned)(n0 + pr0) * K_ + ls16;
  const unsigned offB1 = (unsigned)(n0 + 128 + pr0) * K_ + ls16;

// stage tile T (BK=64: 2 A-loads + 2 B-loads per wave) into buf P (compile-time)
#define STAGE(T, P) do {                                                           \
    const int tc_ = (T) < NT ? (T) : NT - 1;                                       \
    signed char* dA_ = lds + (P) * 32768 + w * 1024;                               \
    gld_lds16(dA_, Aq + (size_t)offA0 + tc_ * 64);                                 \
    gld_lds16(dA_ + 8192, Aq + (size_t)offA1 + tc_ * 64);                          \
    signed char* dB_ = dA_ + 16384;                                                \
    gld_lds16(dB_, Bt + (size_t)offB0 + tc_ * 64);                                 \
    gld_lds16(dB_ + 8192, Bt + (size_t)offB1 + tc_ * 64);                          \
  } while (0)
// read one k-step's fragments into a bank: 4 A-frags + 2 B-frags (6 x ds_read_b128)
#define LDFR(FA, FB, P, KST) do {                                                  \
    const signed char* base_ = lds + (P) * 32768 + ((KST) ? ps1 : ps0);            \
    _Pragma("unroll") for (int mt_ = 0; mt_ < 4; ++mt_)                            \
      FA[mt_] = *(const i32x4*)(base_ + rA + mt_ * 2048);                          \
    _Pragma("unroll") for (int nt_ = 0; nt_ < 2; ++nt_)                            \
      FB[nt_] = *(const i32x4*)(base_ + rB + nt_ * 2048);                          \
  } while (0)
#define MFMA8(FA, FB) do {                                                         \
    _Pragma("unroll") for (int mt_ = 0; mt_ < 4; ++mt_)                            \
    _Pragma("unroll") for (int nt_ = 0; nt_ < 2; ++nt_)                            \
      acc[mt_][nt_] = __builtin_amdgcn_mfma_i32_32x32x32_i8(                       \
          FA[mt_], FB[nt_], acc[mt_][nt_], 0, 0, 0);                               \
  } while (0)
#define BAR do { asm volatile("" ::: "memory");                                    \
                 __builtin_amdgcn_s_barrier();                                     \
                 asm volatile("" ::: "memory"); } while (0)
#define VM4 asm volatile("s_waitcnt vmcnt(4)" ::: "memory")
#define SGB(M, N) __builtin_amdgcn_sched_group_barrier((M), (N), 0)
// per-tile interleave: stages first; fA[mt] reload right after its 2 consumers.
#define SGBPROG do {                                                               \
    SGB(0x10, 4);                                    /* 4 gld_lds early */         \
    SGB(0x8, 2); SGB(0x100, 1); SGB(0x8, 2); SGB(0x100, 1);                        \
    SGB(0x8, 2); SGB(0x100, 1); SGB(0x8, 2); SGB(0x100, 1);  /* c0 + b0-A */       \
    SGB(0x100, 2);                                   /* b0-B */                    \
    SGB(0x8, 2); SGB(0x100, 1); SGB(0x8, 2); SGB(0x100, 1);                        \
    SGB(0x8, 2); SGB(0x100, 1); SGB(0x8, 2); SGB(0x100, 1);  /* c1 + b1-A */       \
    SGB(0x100, 2);                                   /* b1-B */                    \
  } while (0)

// tile T: MFMAs consume banks (loaded during T-1); LDFRs load tile T+1 (buf BUFN);
// stage tile T+3 into buf BUFS. BUFN = (T+1)&3, BUFS = (T+3)&3 (compile-time).
#define KTILE(T, BUFN, BUFS) do {                                                  \
    STAGE((T) + 3, BUFS);                                                          \
    MFMA8(fA0, fB0); LDFR(fA0, fB0, BUFN, 0);                                      \
    MFMA8(fA1, fB1); LDFR(fA1, fB1, BUFN, 1);                                      \
    SGBPROG;                                                                       \
    VM4;  /* drains stage of tile T+2; leaves T+3 in flight */                     \
    BAR;                                                                           \
  } while (0)

  i32x16 acc[4][2] = {};
  i32x4 fA0[4], fB0[2], fA1[4], fB1[2];

  // Prologue: stage tiles 0,1,2 into bufs 0,1,2; drain tiles 0 AND 1 (VM4 — the
  // R10 race was draining only tile 0 here), leaving tile 2 in flight = loop
  // invariant; barrier; read tile0 into banks.
  STAGE(0, 0); STAGE(1, 1); STAGE(2, 2);
  VM4;
  BAR;
  LDFR(fA0, fB0, 0, 0); LDFR(fA1, fB1, 0, 1);

  for (int t = 0; t < NT; t += 4) {
    KTILE(t, 1, 3);
    KTILE(t + 1, 2, 0);
    KTILE(t + 2, 3, 1);
    KTILE(t + 3, 0, 2);
  }

  // epilogue: y = i32acc * sx[m] * scale[n]
  // C/D 32x32: col = lane&31, row = (reg&3) + 8*(reg>>2) + 4*(lane>>5)
  const int mb = m0 + wr * 128;
  const int nb = n0 + wc * 64;
  const int col = lane & 31;
  const int rhi = (lane >> 5) * 4;
  const float scl0 = scale[nb + col];
  const float scl1 = scale[nb + 32 + col];
#pragma unroll
  for (int mt = 0; mt < 4; ++mt) {
#pragma unroll
    for (int r = 0; r < 16; ++r) {
      const int row = mb + mt * 32 + (r & 3) + (r >> 2) * 8 + rhi;
      const float s = sx[row];
      float* out = C + (size_t)row * N_ + nb + col;
      out[0]  = (float)acc[mt][0][r] * s * scl0;
      out[32] = (float)acc[mt][1][r] * s * scl1;
    }
  }
#undef STAGE
#undef LDFR
#undef MFMA8
#undef BAR
#undef VM4
#undef SGB
#undef SGBPROG
#undef KTILE
}

// ---------------- fallback (only if ws_size too small): tiled fp32 vector GEMM ----------------
__global__ __launch_bounds__(256) void fb_gemm_kernel(const float* __restrict__ X,
                                                      const int* __restrict__ W,
                                                      const float* __restrict__ scale,
                                                      float* __restrict__ Y) {
  __shared__ float xs[16][65];
  __shared__ float ws_[16][65];
  const int bn = blockIdx.x * 64;
  const int bm = blockIdx.y * 64;
  const int tx = threadIdx.x & 15;
  const int ty = threadIdx.x >> 4;
  float acc[4][4] = {};
  for (int k0 = 0; k0 < K_; k0 += 16) {
    for (int i = threadIdx.x; i < 64 * 16; i += 256) {
      int r = i >> 4, c = i & 15;
      xs[c][r] = X[(size_t)(bm + r) * K_ + k0 + c];
    }
    for (int i = threadIdx.x; i < 16 * 64; i += 256) {
      int r = i >> 6, c = i & 63;
      ws_[r][c] = (float)W[(size_t)(k0 + r) * N_ + bn + c];
    }
    __syncthreads();
#pragma unroll
    for (int kk = 0; kk < 16; ++kk) {
      float a[4], b[4];
#pragma unroll
      for (int i = 0; i < 4; ++i) a[i] = xs[kk][ty * 4 + i];
#pragma unroll
      for (int j = 0; j < 4; ++j) b[j] = ws_[kk][tx * 4 + j];
#pragma unroll
      for (int i = 0; i < 4; ++i)
#pragma unroll
        for (int j = 0; j < 4; ++j) acc[i][j] += a[i] * b[j];
    }
    __syncthreads();
  }
#pragma unroll
  for (int i = 0; i < 4; ++i)
#pragma unroll
    for (int j = 0; j < 4; ++j)
      Y[(size_t)(bm + ty * 4 + i) * N_ + bn + tx * 4 + j] = acc[i][j] * scale[bn + tx * 4 + j];
}

extern "C" void kernel_launch(void* const* d_in, const int* in_sizes, int n_in,
                              void* d_out, int out_size, void* d_ws, size_t ws_size,
                              hipStream_t stream) {
  const float* x = (const float*)d_in[0];
  const int* w = (const int*)d_in[1];  // harness materializes int8 weights as int32
  const float* scale = (const float*)d_in[2];
  float* y = (float*)d_out;

  const size_t xq_bytes = (size_t)M_ * K_;
  const size_t sx_off = xq_bytes;
  const size_t wt_off = sx_off + (size_t)M_ * 4;
  const size_t need = wt_off + (size_t)N_ * K_;  // ~161.5 MB

  if (ws_size >= need) {
    signed char* xq = (signed char*)d_ws;
    float* sx = (float*)((char*)d_ws + sx_off);
    signed char* wt = (signed char*)((char*)d_ws + wt_off);
    hipLaunchKernelGGL(quant_x_kernel, dim3(M_), dim3(256), 0, stream, x, xq, sx);
    hipLaunchKernelGGL(transpose_w_kernel, dim3(K_ / 64, N_ / 64), dim3(256), 0, stream, w, wt);
    hipLaunchKernelGGL(gemm_i8_kernel, dim3((M_ / 256) * (N_ / 256)), dim3(512), 0, stream,
                       xq, wt, sx, scale, y);
  } else {
    hipLaunchKernelGGL(fb_gemm_kernel, dim3(N_ / 64, M_ / 64), dim3(256), 0, stream,
                       x, w, scale, y);
  }
}